// Round 1
// 414.924 us; speedup vs baseline: 1.0027x; 1.0027x over previous
//
#include <hip/hip_runtime.h>

#define DD   768
#define OUTN 196
#define NT   13      // n-tiles of 16 (208, last tile clamped)
#define KT   24      // k-steps of 32 (768 = 24*32)

typedef __attribute__((ext_vector_type(8))) _Float16 halfx8;
typedef __attribute__((ext_vector_type(4))) float    f32x4;

// Prep: Wh[n][k] = fp16(W[n][k]*gamma[k]);  Ssum[n] = sum_k (float)Wh[n][k]
// (sum of ROUNDED values so mean-subtraction algebra is exact);
// cvec[n] = b[n] + sum_k beta[k]*W[n][k]  (fp32-exact beta folding).
__global__ __launch_bounds__(256) void wprep_kernel(
    const float* __restrict__ W, const float* __restrict__ gamma,
    const float* __restrict__ beta, const float* __restrict__ bias,
    _Float16* __restrict__ Wh, float* __restrict__ Ssum, float* __restrict__ cvec)
{
    __shared__ float red[2][4];
    const int n   = blockIdx.x;
    const int tid = threadIdx.x;
    float s1 = 0.f, s2 = 0.f;
#pragma unroll
    for (int kk = 0; kk < 3; ++kk) {
        const int k = tid + kk * 256;
        const float w = W[n * DD + k];
        const _Float16 h = (_Float16)(w * gamma[k]);
        Wh[n * DD + k] = h;
        s1 += (float)h;
        s2 += beta[k] * w;
    }
#pragma unroll
    for (int off = 32; off > 0; off >>= 1) {
        s1 += __shfl_xor(s1, off);
        s2 += __shfl_xor(s2, off);
    }
    if ((tid & 63) == 0) { red[0][tid >> 6] = s1; red[1][tid >> 6] = s2; }
    __syncthreads();
    if (tid == 0) {
        Ssum[n] = red[0][0] + red[0][1] + red[0][2] + red[0][3];
        cvec[n] = bias[n] + red[1][0] + red[1][1] + red[1][2] + red[1][3];
    }
}

// One wave = 16 rows x all 196 outputs. No LDS, no barriers, x read once.
// Lane mapping (matches verified 16x16x32 layouts): ln16 = A-row / B-col,
// q = k-quad; C/D: row = q*4+reg, col = ln16.
__global__ __launch_bounds__(256, 4) void fused_ln_linear(
    const float* __restrict__ x, const _Float16* __restrict__ Wh,
    const float* __restrict__ Ssum, const float* __restrict__ cvec,
    float* __restrict__ out)
{
    const int tid  = threadIdx.x;
    const int wv   = tid >> 6;
    const int lane = tid & 63;
    const int ln16 = lane & 15;
    const int q    = lane >> 4;

    const long row0 = (long)blockIdx.x * 64 + wv * 16;   // this wave's 16 rows
    const float* xp = x + (row0 + ln16) * DD + q * 8;

    // W fragment offsets (elements), single uniform base + 32-bit offsets
    int woff[NT];
#pragma unroll
    for (int nt = 0; nt < NT; ++nt) {
        int n = nt * 16 + ln16;
        if (n >= OUTN) n = OUTN - 1;          // clamp loads; store is skipped
        woff[nt] = n * DD + q * 8;
    }

    f32x4 acc[NT];
#pragma unroll
    for (int i = 0; i < NT; ++i) acc[i] = (f32x4){0.f, 0.f, 0.f, 0.f};

    float s = 0.f, ss = 0.f;

#pragma unroll 2
    for (int kt = 0; kt < KT; ++kt) {
        const float4 v0 = *(const float4*)(xp + kt * 32);
        const float4 v1 = *(const float4*)(xp + kt * 32 + 4);
        s  += v0.x + v0.y + v0.z + v0.w + v1.x + v1.y + v1.z + v1.w;
        ss += v0.x * v0.x + v0.y * v0.y + v0.z * v0.z + v0.w * v0.w
            + v1.x * v1.x + v1.y * v1.y + v1.z * v1.z + v1.w * v1.w;
        halfx8 hi, lo;
        hi[0] = (_Float16)v0.x; lo[0] = (_Float16)(v0.x - (float)hi[0]);
        hi[1] = (_Float16)v0.y; lo[1] = (_Float16)(v0.y - (float)hi[1]);
        hi[2] = (_Float16)v0.z; lo[2] = (_Float16)(v0.z - (float)hi[2]);
        hi[3] = (_Float16)v0.w; lo[3] = (_Float16)(v0.w - (float)hi[3]);
        hi[4] = (_Float16)v1.x; lo[4] = (_Float16)(v1.x - (float)hi[4]);
        hi[5] = (_Float16)v1.y; lo[5] = (_Float16)(v1.y - (float)hi[5]);
        hi[6] = (_Float16)v1.z; lo[6] = (_Float16)(v1.z - (float)hi[6]);
        hi[7] = (_Float16)v1.w; lo[7] = (_Float16)(v1.w - (float)hi[7]);
#pragma unroll
        for (int nt = 0; nt < NT; ++nt) {
            const halfx8 bw = *(const halfx8*)(Wh + woff[nt] + kt * 32);
            acc[nt] = __builtin_amdgcn_mfma_f32_16x16x32_f16(hi, bw, acc[nt], 0, 0, 0);
            acc[nt] = __builtin_amdgcn_mfma_f32_16x16x32_f16(lo, bw, acc[nt], 0, 0, 0);
        }
    }

    // Row stats: this lane's row (ln16) lives in exactly 4 lanes (q=0..3)
    s  += __shfl_xor(s, 16);  s  += __shfl_xor(s, 32);
    ss += __shfl_xor(ss, 16); ss += __shfl_xor(ss, 32);
    const float mean_r = s * (1.f / DD);
    const float rstd_r = rsqrtf(ss * (1.f / DD) - mean_r * mean_r + 1e-6f);

    // Broadcast stats for this lane's 4 OUTPUT rows (q*4+rg); lanes 0..15
    // hold fully-reduced stats for rows 0..15.
    float mb[4], rb[4];
#pragma unroll
    for (int rg = 0; rg < 4; ++rg) {
        const int src = q * 4 + rg;
        mb[rg] = __shfl(mean_r, src);
        rb[rg] = __shfl(rstd_r, src);
    }

    const long obase = (row0 + q * 4) * OUTN;
#pragma unroll
    for (int nt = 0; nt < NT; ++nt) {
        const int n = nt * 16 + ln16;
        if (n < OUTN) {
            const float Sp = Ssum[n];
            const float cn = cvec[n];
#pragma unroll
            for (int rg = 0; rg < 4; ++rg)
                out[obase + rg * OUTN + n] = rb[rg] * (acc[nt][rg] - mb[rg] * Sp) + cn;
        }
    }
}

extern "C" void kernel_launch(void* const* d_in, const int* in_sizes, int n_in,
                              void* d_out, int out_size, void* d_ws, size_t ws_size,
                              hipStream_t stream) {
    const float* x     = (const float*)d_in[0];
    const float* gamma = (const float*)d_in[1];
    const float* beta  = (const float*)d_in[2];
    const float* W     = (const float*)d_in[3];
    const float* b     = (const float*)d_in[4];
    float* out = (float*)d_out;

    _Float16* Wh  = (_Float16*)d_ws;                                  // 301,056 B
    float*    Ss  = (float*)((char*)d_ws + OUTN * DD * sizeof(_Float16));
    float*    cv  = Ss + OUTN;                                        // total ~302.6 KB

    wprep_kernel<<<OUTN, 256, 0, stream>>>(W, gamma, beta, b, Wh, Ss, cv);

    const long rows = 16L * 4096;                                     // 65536
    fused_ln_linear<<<rows / 64, 256, 0, stream>>>(x, Wh, Ss, cv, out);
}

// Round 3
// 348.000 us; speedup vs baseline: 1.1955x; 1.1923x over previous
//
#include <hip/hip_runtime.h>

#define DD    768
#define OUTN  196
#define NSLOT 96          // 16B chunks per W row (768 halfs * 2B / 16B)

typedef __attribute__((ext_vector_type(8))) _Float16 halfx8;
typedef __attribute__((ext_vector_type(4))) float    f32x4;

// Prep: Wh[n][k] = fp16(W[n][k]*gamma[k]);  Ssum[n] = sum_k (float)Wh[n][k]
// (sum of ROUNDED values so the mean-subtraction fold is exact);
// cvec[n] = b[n] + sum_k beta[k]*W[n][k].
__global__ __launch_bounds__(256) void wprep_kernel(
    const float* __restrict__ W, const float* __restrict__ gamma,
    const float* __restrict__ beta, const float* __restrict__ bias,
    _Float16* __restrict__ Wh, float* __restrict__ Ssum, float* __restrict__ cvec)
{
    __shared__ float red[2][4];
    const int n   = blockIdx.x;
    const int tid = threadIdx.x;
    float s1 = 0.f, s2 = 0.f;
#pragma unroll
    for (int kk = 0; kk < 3; ++kk) {
        const int k = tid + kk * 256;
        const float w = W[n * DD + k];
        const _Float16 h = (_Float16)(w * gamma[k]);
        Wh[n * DD + k] = h;
        s1 += (float)h;
        s2 += beta[k] * w;
    }
#pragma unroll
    for (int off = 32; off > 0; off >>= 1) {
        s1 += __shfl_xor(s1, off);
        s2 += __shfl_xor(s2, off);
    }
    if ((tid & 63) == 0) { red[0][tid >> 6] = s1; red[1][tid >> 6] = s2; }
    __syncthreads();
    if (tid == 0) {
        Ssum[n] = red[0][0] + red[0][1] + red[0][2] + red[0][3];
        cvec[n] = bias[n] + red[1][0] + red[1][1] + red[1][2] + red[1][3];
    }
}

// One block = 1024 threads = 16 waves, one N-part of W resident in LDS.
// Each wave owns 16 rows; k-loop has NO barriers, NO global W loads.
// LDS layout: row r (part-local), 16B-slot s stored at slot s^(r&7):
// conflict-free ds_read_b128 for the MFMA B-fragment (lane ln16 = row,
// q = k-quad reads slot kt*4+q of row tile*16+ln16).
template <int T, int N0, int PR>
__device__ __forceinline__ void run_part(
    const float* __restrict__ x, const _Float16* __restrict__ Wh,
    const float* __restrict__ Ssum, const float* __restrict__ cvec,
    float* __restrict__ out, _Float16* ldsW, int mblk)
{
    const int tid = threadIdx.x;

    // ---- stage W part into LDS (once), coalesced global, conflict-free write
    for (int ci = tid; ci < NSLOT * PR; ci += 1024) {
        const int r  = ci / NSLOT;
        const int sl = ci - r * NSLOT;
        int nrow = N0 + r;
        if (nrow > OUTN - 1) nrow = OUTN - 1;      // clamp pad rows (never stored)
        const halfx8 w = *(const halfx8*)(Wh + nrow * DD + sl * 8);
        *(halfx8*)(ldsW + (r * NSLOT + (sl ^ (r & 7))) * 8) = w;
    }
    __syncthreads();

    const int wv   = tid >> 6;
    const int lane = tid & 63;
    const int ln16 = lane & 15;
    const int q    = lane >> 4;
    const int rx   = ln16 & 7;                     // (tile*16+ln16)&7 == ln16&7

    const long row0 = (long)mblk * 256 + wv * 16;  // this wave's 16 rows
    const float* xp = x + (row0 + ln16) * DD + q * 8;

    int rbase[T];                                  // per-tile LDS row base (elems)
#pragma unroll
    for (int t = 0; t < T; ++t) rbase[t] = (t * 16 + ln16) * DD;

    f32x4 acc[T];
#pragma unroll
    for (int t = 0; t < T; ++t) acc[t] = (f32x4){0.f, 0.f, 0.f, 0.f};

    float s = 0.f, ss = 0.f;

#pragma unroll
    for (int kt = 0; kt < 24; ++kt) {
        const float4 v0 = *(const float4*)(xp + kt * 32);
        const float4 v1 = *(const float4*)(xp + kt * 32 + 4);
        s  += (v0.x + v0.y) + (v0.z + v0.w) + (v1.x + v1.y) + (v1.z + v1.w);
        ss  = fmaf(v0.x, v0.x, ss); ss = fmaf(v0.y, v0.y, ss);
        ss  = fmaf(v0.z, v0.z, ss); ss = fmaf(v0.w, v0.w, ss);
        ss  = fmaf(v1.x, v1.x, ss); ss = fmaf(v1.y, v1.y, ss);
        ss  = fmaf(v1.z, v1.z, ss); ss = fmaf(v1.w, v1.w, ss);

        halfx8 hi, lo;
        hi[0] = (_Float16)v0.x; lo[0] = (_Float16)(v0.x - (float)hi[0]);
        hi[1] = (_Float16)v0.y; lo[1] = (_Float16)(v0.y - (float)hi[1]);
        hi[2] = (_Float16)v0.z; lo[2] = (_Float16)(v0.z - (float)hi[2]);
        hi[3] = (_Float16)v0.w; lo[3] = (_Float16)(v0.w - (float)hi[3]);
        hi[4] = (_Float16)v1.x; lo[4] = (_Float16)(v1.x - (float)hi[4]);
        hi[5] = (_Float16)v1.y; lo[5] = (_Float16)(v1.y - (float)hi[5]);
        hi[6] = (_Float16)v1.z; lo[6] = (_Float16)(v1.z - (float)hi[6]);
        hi[7] = (_Float16)v1.w; lo[7] = (_Float16)(v1.w - (float)hi[7]);

#pragma unroll
        for (int t = 0; t < T; ++t) {
            const int slot = (kt * 4 + q) ^ rx;
            const halfx8 bw = *(const halfx8*)(ldsW + rbase[t] + slot * 8);
            acc[t] = __builtin_amdgcn_mfma_f32_16x16x32_f16(hi, bw, acc[t], 0, 0, 0);
            acc[t] = __builtin_amdgcn_mfma_f32_16x16x32_f16(lo, bw, acc[t], 0, 0, 0);
        }
    }

    // ---- row stats: lane's row lives in 4 lanes (q=0..3) -> 2 xors each
    s  += __shfl_xor(s, 16);  s  += __shfl_xor(s, 32);
    ss += __shfl_xor(ss, 16); ss += __shfl_xor(ss, 32);
    const float mean_r = s * (1.f / DD);
    const float rstd_r = rsqrtf(ss * (1.f / DD) - mean_r * mean_r + 1e-6f);

    float mb[4], rb[4];
#pragma unroll
    for (int rg = 0; rg < 4; ++rg) {              // stats for output rows q*4+rg
        mb[rg] = __shfl(mean_r, q * 4 + rg);
        rb[rg] = __shfl(rstd_r, q * 4 + rg);
    }

    const long obase = (row0 + q * 4) * OUTN;
#pragma unroll
    for (int t = 0; t < T; ++t) {
        const int n = N0 + t * 16 + ln16;
        if (n < OUTN) {
            const float Sp = Ssum[n];
            const float cn = cvec[n];
#pragma unroll
            for (int rg = 0; rg < 4; ++rg)
                out[obase + rg * OUTN + n] = rb[rg] * (acc[t][rg] - mb[rg] * Sp) + cn;
        }
    }
}

__global__ __launch_bounds__(1024, 4) void fused_ln_linear(
    const float* __restrict__ x, const _Float16* __restrict__ Wh,
    const float* __restrict__ Ssum, const float* __restrict__ cvec,
    float* __restrict__ out)
{
    __shared__ _Float16 ldsW[80 * NSLOT * 8];     // 122,880 B (largest part)
    const int part = blockIdx.x % 3;              // 3 consecutive bids share m -> L3 reuse
    const int m    = blockIdx.x / 3;
    if (part == 0)      run_part<5,   0, 80>(x, Wh, Ssum, cvec, out, ldsW, m);
    else if (part == 1) run_part<4,  80, 64>(x, Wh, Ssum, cvec, out, ldsW, m);
    else                run_part<4, 144, 64>(x, Wh, Ssum, cvec, out, ldsW, m);
}

extern "C" void kernel_launch(void* const* d_in, const int* in_sizes, int n_in,
                              void* d_out, int out_size, void* d_ws, size_t ws_size,
                              hipStream_t stream) {
    const float* x     = (const float*)d_in[0];
    const float* gamma = (const float*)d_in[1];
    const float* beta  = (const float*)d_in[2];
    const float* W     = (const float*)d_in[3];
    const float* b     = (const float*)d_in[4];
    float* out = (float*)d_out;

    _Float16* Wh = (_Float16*)d_ws;                                   // 301,056 B
    float*    Ss = (float*)((char*)d_ws + OUTN * DD * sizeof(_Float16));
    float*    cv = Ss + OUTN;

    wprep_kernel<<<OUTN, 256, 0, stream>>>(W, gamma, beta, b, Wh, Ss, cv);

    // 65536 rows / 256 rows-per-block = 256 m-chunks, x3 N-parts
    fused_ln_linear<<<256 * 3, 1024, 0, stream>>>(x, Wh, Ss, cv, out);
}